// Round 1
// baseline (1050.484 us; speedup 1.0000x reference)
//
#include <hip/hip_runtime.h>
#include <math.h>

#define NTOT 8704
#define BANKN 8192
#define NB 512
#define DIM 128
#define TEMP_F 0.07f
#define TR 64
#define TCOL 64
#define NTILE (NTOT / TCOL)   // 136
#define NCHUNK 4
#define TPC (NTILE / NCHUNK)  // 34
#define LSTR 129              // LDS row stride in floats (odd -> conflict-free-ish)

// ---------------- pack: bank (D x BANK) -> cf rows [0, 8192) ----------------
__global__ void pack_bank_kernel(const float* __restrict__ bank1,
                                 const float* __restrict__ bank2,
                                 float* __restrict__ cf1,
                                 float* __restrict__ cf2) {
  const float* src = (blockIdx.z == 0) ? bank2 : bank1;  // cf1 <- bank2, cf2 <- bank1
  float* dst = (blockIdx.z == 0) ? cf1 : cf2;
  __shared__ float tile[32][33];
  int tx = threadIdx.x, ty = threadIdx.y;
  int bx = blockIdx.x, by = blockIdx.y;
  int col = bx * 32 + tx;
#pragma unroll
  for (int s = 0; s < 32; s += 8)
    tile[ty + s][tx] = src[(by * 32 + ty + s) * BANKN + col];
  __syncthreads();
  int k = by * 32 + tx;
#pragma unroll
  for (int s = 0; s < 32; s += 8)
    dst[(bx * 32 + ty + s) * DIM + k] = tile[tx][ty + s];
}

// ---------------- pack: features (2B,128) -> cf rows [8192, 8704) -----------
__global__ void pack_feat_kernel(const float* __restrict__ feats,
                                 float* __restrict__ cf1,
                                 float* __restrict__ cf2) {
  int t = blockIdx.x * blockDim.x + threadIdx.x;  // over 2*NB*DIM/4 float4s
  const int total = (2 * NB * DIM) / 4;           // 32768
  if (t < total) {
    float4 v = reinterpret_cast<const float4*>(feats)[t];
    const int half = total / 2;  // 16384
    if (t < half)
      reinterpret_cast<float4*>(cf1 + (size_t)BANKN * DIM)[t] = v;
    else
      reinterpret_cast<float4*>(cf2 + (size_t)BANKN * DIM)[t - half] = v;
  }
}

// ---------------- main: streamed masked-softmax reductions ------------------
// partials layout: [branch][chunk][3 (Z,P,C)][NTOT]
__global__ __launch_bounds__(256) void supcon_main_kernel(
    const float* __restrict__ cf1, const float* __restrict__ cf2,
    const int* __restrict__ bank_labels, const int* __restrict__ label,
    float* __restrict__ partials) {
  const int rb = blockIdx.x;      // row block 0..135
  const int chunk = blockIdx.y;   // 0..NCHUNK-1
  const int branch = blockIdx.z;  // 0..1
  const float* __restrict__ cf = branch ? cf2 : cf1;

  __shared__ float At[TR][LSTR];
  __shared__ float Bt[TCOL][LSTR];
  __shared__ int clab[TCOL];

  const int tid = threadIdx.x;
  const int trg = tid >> 4;   // 0..15 row group
  const int tcg = tid & 15;   // 0..15 col group
  const int row0 = rb * TR;

  // stage A tile once (64 rows x 128 k), coalesced global, 2-way LDS aliasing
#pragma unroll
  for (int rep = 0; rep < 32; ++rep) {
    int f = rep * 256 + tid;
    int r = f >> 7, k = f & 127;
    At[r][k] = cf[(row0 + r) * DIM + k];
  }

  int rlab[4];
#pragma unroll
  for (int i = 0; i < 4; ++i) {
    int gr = row0 + trg * 4 + i;
    rlab[i] = (gr < BANKN) ? bank_labels[gr] : label[gr - BANKN];
  }

  const float invT = 1.0f / TEMP_F;
  const float M = invT;  // exact row max (normalized rows -> diag = 1/T)
  float Zacc[4] = {0.f, 0.f, 0.f, 0.f};
  float Pacc[4] = {0.f, 0.f, 0.f, 0.f};
  float Cacc[4] = {0.f, 0.f, 0.f, 0.f};

  for (int t = 0; t < TPC; ++t) {
    const int col0 = (chunk * TPC + t) * TCOL;
    __syncthreads();  // previous tile fully consumed (also covers A staging)
#pragma unroll
    for (int rep = 0; rep < 32; ++rep) {
      int f = rep * 256 + tid;
      int r = f >> 7, k = f & 127;
      Bt[r][k] = cf[(col0 + r) * DIM + k];
    }
    if (tid < TCOL) {
      int gc = col0 + tid;
      clab[tid] = (gc < BANKN) ? bank_labels[gc] : label[gc - BANKN];
    }
    __syncthreads();

    float acc[4][4] = {};
#pragma unroll 4
    for (int k = 0; k < DIM; ++k) {
      float a[4], b[4];
#pragma unroll
      for (int i = 0; i < 4; ++i) a[i] = At[trg * 4 + i][k];
#pragma unroll
      for (int j = 0; j < 4; ++j) b[j] = Bt[tcg * 4 + j][k];
#pragma unroll
      for (int i = 0; i < 4; ++i)
#pragma unroll
        for (int j = 0; j < 4; ++j) acc[i][j] = fmaf(a[i], b[j], acc[i][j]);
    }

    // epilogue: masked accumulation
#pragma unroll
    for (int i = 0; i < 4; ++i) {
      const int gr = row0 + trg * 4 + i;
#pragma unroll
      for (int j = 0; j < 4; ++j) {
        const int gc = col0 + tcg * 4 + j;
        const int cl = clab[tcg * 4 + j];
        const float l = acc[i][j] * invT;
        const bool same = (rlab[i] == cl);
        const float e = __expf(l - M);
        Zacc[i] += same ? 0.f : e;
        const bool pos = same && (gr != gc);
        Pacc[i] += pos ? l : 0.f;
        Cacc[i] += pos ? 1.f : 0.f;
      }
    }
  }

  // cross-thread (tcg) reduction via LDS scratch (reuse At)
  __syncthreads();
  float* sZ = &At[0][0];
  float* sP = sZ + TR * 16;
  float* sC = sP + TR * 16;
#pragma unroll
  for (int i = 0; i < 4; ++i) {
    int r = trg * 4 + i;
    sZ[r * 16 + tcg] = Zacc[i];
    sP[r * 16 + tcg] = Pacc[i];
    sC[r * 16 + tcg] = Cacc[i];
  }
  __syncthreads();
  if (tid < TR) {
    float z = 0.f, p = 0.f, c = 0.f;
    for (int q = 0; q < 16; ++q) {
      z += sZ[tid * 16 + q];
      p += sP[tid * 16 + q];
      c += sC[tid * 16 + q];
    }
    const int base = ((branch * NCHUNK + chunk) * 3) * NTOT + row0 + tid;
    partials[base] = z;
    partials[base + NTOT] = p;
    partials[base + 2 * NTOT] = c;
  }
}

// ---------------- finisher: combine partials -> scalar loss -----------------
__global__ void supcon_final_kernel(const float* __restrict__ partials,
                                    float* __restrict__ out) {
  __shared__ float red[256];
  const float invT = 1.0f / TEMP_F;
  const float M = invT;
  float local = 0.f;
  for (int idx = threadIdx.x; idx < 2 * NTOT; idx += 256) {
    const int branch = idx / NTOT, row = idx - branch * NTOT;
    float z = 0.f, p = 0.f, c = 0.f;
    for (int ch = 0; ch < NCHUNK; ++ch) {
      const int base = ((branch * NCHUNK + ch) * 3) * NTOT + row;
      z += partials[base];
      p += partials[base + NTOT];
      c += partials[base + 2 * NTOT];
    }
    const float denom = M + logf(z);
    local += -(p / c - denom);
  }
  red[threadIdx.x] = local;
  __syncthreads();
  for (int s = 128; s > 0; s >>= 1) {
    if (threadIdx.x < s) red[threadIdx.x] += red[threadIdx.x + s];
    __syncthreads();
  }
  if (threadIdx.x == 0) {
    const float v = red[0] / (2.0f * NTOT);
    out[0] = v;
    out[1] = v;
    out[2] = v;
  }
}

// ---------------------------------------------------------------------------
extern "C" void kernel_launch(void* const* d_in, const int* in_sizes, int n_in,
                              void* d_out, int out_size, void* d_ws,
                              size_t ws_size, hipStream_t stream) {
  const float* features = (const float*)d_in[0];      // (1024,1,128) f32
  const int* label = (const int*)d_in[1];             // (512,) i32
  const float* bank1 = (const float*)d_in[2];         // (128,8192) f32
  const float* bank2 = (const float*)d_in[3];         // (128,8192) f32
  const int* bank_labels = (const int*)d_in[4];       // (8192,) i32
  float* out = (float*)d_out;

  float* cf1 = (float*)d_ws;                          // NTOT*DIM
  float* cf2 = cf1 + (size_t)NTOT * DIM;              // NTOT*DIM
  float* partials = cf2 + (size_t)NTOT * DIM;         // 2*NCHUNK*3*NTOT

  // pack cf1 = [bank2^T ; f1], cf2 = [bank1^T ; f2]
  pack_bank_kernel<<<dim3(BANKN / 32, DIM / 32, 2), dim3(32, 8), 0, stream>>>(
      bank1, bank2, cf1, cf2);
  pack_feat_kernel<<<dim3((2 * NB * DIM / 4 + 255) / 256), dim3(256), 0,
                     stream>>>(features, cf1, cf2);

  // main streamed reduction
  supcon_main_kernel<<<dim3(NTILE, NCHUNK, 2), dim3(256), 0, stream>>>(
      cf1, cf2, bank_labels, label, partials);

  // finisher
  supcon_final_kernel<<<dim3(1), dim3(256), 0, stream>>>(partials, out);
}

// Round 2
// 154.436 us; speedup vs baseline: 6.8021x; 6.8021x over previous
//
#include <hip/hip_runtime.h>
#include <math.h>

#define NTOT 8704
#define BANKN 8192
#define NB 512
#define DIM 128
#define INVT (1.0f / 0.07f)
#define NCHUNK 8
#define TPC 17          // col tiles per chunk (17*64*8 = 8704)
#define BN 64           // cols per tile

using short8 = __attribute__((ext_vector_type(8))) short;
using f32x4 = __attribute__((ext_vector_type(4))) float;

static __device__ __forceinline__ ushort f2bf(float f) {
  union { float f; unsigned u; } v;
  v.f = f;
  unsigned r = v.u + 0x7fffu + ((v.u >> 16) & 1u);  // RNE
  return (ushort)(r >> 16);
}

// ---------------- pack: bank (D x BANK) fp32 -> cf rows [0, 8192) bf16 ------
__global__ void pack_bank_kernel(const float* __restrict__ bank1,
                                 const float* __restrict__ bank2,
                                 ushort* __restrict__ cf1b,
                                 ushort* __restrict__ cf2b) {
  const float* src = (blockIdx.z == 0) ? bank2 : bank1;  // cf1 <- bank2, cf2 <- bank1
  ushort* dst = (blockIdx.z == 0) ? cf1b : cf2b;
  __shared__ float tile[32][33];
  int tx = threadIdx.x, ty = threadIdx.y;
  int bx = blockIdx.x, by = blockIdx.y;
  int col = bx * 32 + tx;
#pragma unroll
  for (int s = 0; s < 32; s += 8)
    tile[ty + s][tx] = src[(by * 32 + ty + s) * BANKN + col];
  __syncthreads();
  int k = by * 32 + tx;
#pragma unroll
  for (int s = 0; s < 32; s += 8)
    dst[(size_t)(bx * 32 + ty + s) * DIM + k] = f2bf(tile[tx][ty + s]);
}

// ---------------- pack: features (2B,128) fp32 -> cf rows [8192, 8704) ------
__global__ void pack_feat_kernel(const float* __restrict__ feats,
                                 ushort* __restrict__ cf1b,
                                 ushort* __restrict__ cf2b) {
  int t = blockIdx.x * blockDim.x + threadIdx.x;  // over 2*NB*DIM/4 float4s
  const int total = (2 * NB * DIM) / 4;           // 32768
  if (t < total) {
    float4 v = reinterpret_cast<const float4*>(feats)[t];
    ushort4 o;
    o.x = f2bf(v.x); o.y = f2bf(v.y); o.z = f2bf(v.z); o.w = f2bf(v.w);
    const int half = total / 2;  // 16384
    if (t < half)
      reinterpret_cast<ushort4*>(cf1b + (size_t)BANKN * DIM)[t] = o;
    else
      reinterpret_cast<ushort4*>(cf2b + (size_t)BANKN * DIM)[t - half] = o;
  }
}

// ---------------- labels + class histogram (single block) -------------------
__global__ void pack_lab_kernel(const int* __restrict__ bank_labels,
                                const int* __restrict__ label,
                                int* __restrict__ lab_all,
                                int* __restrict__ cnt) {
  __shared__ int h[100];
  const int tid = threadIdx.x;
  if (tid < 100) h[tid] = 0;
  __syncthreads();
  for (int i = tid; i < NTOT; i += 256) {
    const int v = (i < BANKN) ? bank_labels[i] : label[i - BANKN];
    lab_all[i] = v;
    atomicAdd(&h[v], 1);
  }
  __syncthreads();
  if (tid < 100) cnt[tid] = h[tid];
}

// ---------------- main: MFMA QK^T-style masked-softmax reductions -----------
// partials layout: [branch][chunk][2 (Z,P)][NTOT]
__global__ __launch_bounds__(256) void supcon_mfma_kernel(
    const ushort* __restrict__ cf1b, const ushort* __restrict__ cf2b,
    const int* __restrict__ lab_all, float* __restrict__ partials) {
  const int rb = blockIdx.x;      // 0..67 row block (128 rows)
  const int chunk = blockIdx.y;   // 0..7
  const int branch = blockIdx.z;  // 0..1
  const ushort* __restrict__ cf = branch ? cf2b : cf1b;

  const int tid = threadIdx.x;
  const int wid = tid >> 6, lane = tid & 63;
  const int l15 = lane & 15, l4 = lane >> 4;
  const int rowW = rb * 128 + wid * 32;  // wave owns rows [rowW, rowW+32)

  __shared__ ushort Bt[2][BN * DIM];  // 2 x 16KB, linear layout, swizzled content

  // ---- A fragments in registers: rows rowW..rowW+31, full K=128 ----
  short8 a[2][4];
#pragma unroll
  for (int rt = 0; rt < 2; ++rt) {
    const int r = rowW + rt * 16 + l15;
#pragma unroll
    for (int ks = 0; ks < 4; ++ks)
      a[rt][ks] = *reinterpret_cast<const short8*>(cf + (size_t)r * DIM + ks * 32 + l4 * 8);
  }
  int rlab[2][4];
#pragma unroll
  for (int rt = 0; rt < 2; ++rt)
#pragma unroll
    for (int rg = 0; rg < 4; ++rg)
      rlab[rt][rg] = lab_all[rowW + rt * 16 + l4 * 4 + rg];

  float Zr[2][4] = {{0.f, 0.f, 0.f, 0.f}, {0.f, 0.f, 0.f, 0.f}};
  float Pr[2][4] = {{0.f, 0.f, 0.f, 0.f}, {0.f, 0.f, 0.f, 0.f}};

  // ---- stage helper: global -> LDS, linear dest, inverse-swizzled source ----
  // read side uses chunk' = chunk ^ (row&7); source pre-applies same XOR.
  auto STAGE = [&](int t, int buf) {
    const int col0 = (chunk * TPC + t) * BN;
#pragma unroll
    for (int it = 0; it < 4; ++it) {
      const int o = it * 256 + tid;           // 16B-chunk index 0..1023
      const int row = o >> 4, cc = o & 15;
      const ushort* src = cf + (size_t)(col0 + row) * DIM + ((cc ^ (row & 7)) * 8);
      ushort* dst = &Bt[buf][(it * 256 + wid * 64) * 8];  // wave-uniform base
      __builtin_amdgcn_global_load_lds(
          (const __attribute__((address_space(1))) void*)src,
          (__attribute__((address_space(3))) void*)dst, 16, 0, 0);
    }
  };

  STAGE(0, 0);
  asm volatile("s_waitcnt vmcnt(0)" ::: "memory");
  __syncthreads();

  const float c2 = INVT;
  int cur = 0;
  for (int t = 0; t < TPC; ++t) {
    if (t + 1 < TPC) STAGE(t + 1, cur ^ 1);

    const int col0 = (chunk * TPC + t) * BN;
    int clab[4];
#pragma unroll
    for (int ct = 0; ct < 4; ++ct) clab[ct] = lab_all[col0 + ct * 16 + l15];

    f32x4 acc[2][4];
#pragma unroll
    for (int rt = 0; rt < 2; ++rt)
#pragma unroll
      for (int ct = 0; ct < 4; ++ct) acc[rt][ct] = (f32x4){0.f, 0.f, 0.f, 0.f};

#pragma unroll
    for (int ks = 0; ks < 4; ++ks) {
      short8 b[4];
#pragma unroll
      for (int ct = 0; ct < 4; ++ct) {
        const int r = ct * 16 + l15;
        const int swz = (ks * 4 + l4) ^ (r & 7);
        b[ct] = *reinterpret_cast<const short8*>(&Bt[cur][r * DIM + swz * 8]);
      }
#pragma unroll
      for (int rt = 0; rt < 2; ++rt)
#pragma unroll
        for (int ct = 0; ct < 4; ++ct)
          acc[rt][ct] = __builtin_amdgcn_mfma_f32_16x16x32_bf16(
              a[rt][ks], b[ct], acc[rt][ct], 0, 0, 0);
    }

    // epilogue: Z += !same * exp((v-1)/T); P += same * v
#pragma unroll
    for (int ct = 0; ct < 4; ++ct) {
      const int cl = clab[ct];
#pragma unroll
      for (int rt = 0; rt < 2; ++rt)
#pragma unroll
        for (int rg = 0; rg < 4; ++rg) {
          const float v = acc[rt][ct][rg];
          const float e = __expf(fmaf(v, c2, -c2));
          const bool same = (rlab[rt][rg] == cl);
          Zr[rt][rg] += same ? 0.0f : e;
          Pr[rt][rg] += same ? v : 0.0f;
        }
    }

    asm volatile("s_waitcnt vmcnt(0)" ::: "memory");
    __syncthreads();
    cur ^= 1;
  }

  // ---- cross-lane reduction: sum over the 16 lanes sharing (lane>>4) ----
#pragma unroll
  for (int rt = 0; rt < 2; ++rt)
#pragma unroll
    for (int rg = 0; rg < 4; ++rg) {
      float z = Zr[rt][rg], p = Pr[rt][rg];
#pragma unroll
      for (int off = 1; off < 16; off <<= 1) {
        z += __shfl_xor(z, off);
        p += __shfl_xor(p, off);
      }
      if (l15 == 0) {
        const int row = rowW + rt * 16 + l4 * 4 + rg;
        const size_t base = (size_t)(branch * NCHUNK + chunk) * 2 * NTOT;
        partials[base + row] = z;
        partials[base + NTOT + row] = p;
      }
    }
}

// ---------------- loss stage 1: per-row loss, per-block partial sums --------
__global__ void loss_part_kernel(const float* __restrict__ partials,
                                 const int* __restrict__ lab_all,
                                 const int* __restrict__ cnt,
                                 float* __restrict__ red) {
  const int bx = blockIdx.x, branch = blockIdx.y;
  const int tid = threadIdx.x;
  float local = 0.f;
  if (tid < 128) {
    const int row = bx * 128 + tid;
    float z = 0.f, p = 0.f;
    for (int ch = 0; ch < NCHUNK; ++ch) {
      const size_t base = (size_t)(branch * NCHUNK + ch) * 2 * NTOT;
      z += partials[base + row];
      p += partials[base + NTOT + row];
    }
    const float C = (float)(cnt[lab_all[row]] - 1);
    const float denom = INVT + logf(z);
    local = -((INVT * (p - 1.0f)) / C - denom);
  }
  __shared__ float s[256];
  s[tid] = local;
  __syncthreads();
  for (int st = 128; st > 0; st >>= 1) {
    if (tid < st) s[tid] += s[tid + st];
    __syncthreads();
  }
  if (tid == 0) red[branch * 68 + bx] = s[0];
}

// ---------------- loss stage 2: final scalar --------------------------------
__global__ void loss_final_kernel(const float* __restrict__ red,
                                  float* __restrict__ out) {
  const int tid = threadIdx.x;
  __shared__ float s[256];
  s[tid] = (tid < 136) ? red[tid] : 0.f;
  __syncthreads();
  for (int st = 128; st > 0; st >>= 1) {
    if (tid < st) s[tid] += s[tid + st];
    __syncthreads();
  }
  if (tid == 0) {
    const float v = s[0] / (2.0f * NTOT);
    out[0] = v; out[1] = v; out[2] = v;
  }
}

// ---------------------------------------------------------------------------
extern "C" void kernel_launch(void* const* d_in, const int* in_sizes, int n_in,
                              void* d_out, int out_size, void* d_ws,
                              size_t ws_size, hipStream_t stream) {
  const float* features = (const float*)d_in[0];      // (1024,1,128) f32
  const int* label = (const int*)d_in[1];             // (512,) i32
  const float* bank1 = (const float*)d_in[2];         // (128,8192) f32
  const float* bank2 = (const float*)d_in[3];         // (128,8192) f32
  const int* bank_labels = (const int*)d_in[4];       // (8192,) i32
  float* out = (float*)d_out;

  char* ws = (char*)d_ws;
  ushort* cf1b = (ushort*)(ws);                              // 2,228,224 B
  ushort* cf2b = (ushort*)(ws + 2228224);                    // 2,228,224 B
  int* lab_all = (int*)(ws + 4456448);                       // 34,816 B
  int* cnt = (int*)(ws + 4491264);                           // 400 B
  float* partials = (float*)(ws + 4491776);                  // 1,114,112 B
  float* red = (float*)(ws + 5605888);                       // 544 B

  pack_bank_kernel<<<dim3(BANKN / 32, DIM / 32, 2), dim3(32, 8), 0, stream>>>(
      bank1, bank2, cf1b, cf2b);
  pack_feat_kernel<<<dim3((2 * NB * DIM / 4 + 255) / 256), dim3(256), 0,
                     stream>>>(features, cf1b, cf2b);
  pack_lab_kernel<<<dim3(1), dim3(256), 0, stream>>>(bank_labels, label,
                                                     lab_all, cnt);

  supcon_mfma_kernel<<<dim3(NTOT / 128, NCHUNK, 2), dim3(256), 0, stream>>>(
      cf1b, cf2b, lab_all, partials);

  loss_part_kernel<<<dim3(68, 2), dim3(256), 0, stream>>>(partials, lab_all,
                                                          cnt, red);
  loss_final_kernel<<<dim3(1), dim3(256), 0, stream>>>(red, out);
}